// Round 21
// baseline (247.620 us; speedup 1.0000x reference)
//
#include <hip/hip_runtime.h>

typedef unsigned long long ull;

#define BB 64
#define PP 25600
#define OO 32
#define TH 0.35f
#define GX 25
#define NTASK 12800          // 64 batches x 200 segments of 128 positions

// ws layout
#define WS_BP     0           // 16384 B (zeroed by k_hist block 0; bp==0 <=> all-zero row -> p=0)
#define WS_LSUM   16384       // 256 B (zeroed by k_hist block 1)
#define WS_CSUM   16640
#define WS_NPOS   16896
#define WS_SS     17152
#define WS_DONE   17408       // ticket (int) ; task cursor at +4
#define WS_HISTP  17664       // 25600 B
#define WS_CURS   43264       // 1024 B (per-cell cursors, zeroed by k_hist block 1)
#define WS_IPOS   44288       // 102400 B
#define WS_PF4    146688      // 409600 B
#define WS_META   556288      // 204800 B
#define WS_VALS   761088      // 6553600 B

__device__ __forceinline__ float sl1f(float d){
    float ad = fabsf(d);
    return ad < 1.f ? 0.5f*ad*ad : ad - 0.5f;
}

__device__ __forceinline__ float locloss(float x0,float y0,float x1,float y1,
                                         float4 pr, float4 ld){
    float gx = ((x0+x1)*0.5f - pr.x) / (0.1f*pr.z);
    float gy = ((y0+y1)*0.5f - pr.y) / (0.1f*pr.w);
    float gw = logf((x1-x0)/pr.z) / 0.2f;
    float gh = logf((y1-y0)/pr.w) / 0.2f;
    return sl1f(ld.x-gx)+sl1f(ld.y-gy)+sl1f(ld.z-gw)+sl1f(ld.w-gh);
}

// DPP cross-lane max/min (old=v, bound_ctrl=false -> invalid lanes identity).
template<int CTRL>
__device__ __forceinline__ float dpp_maxf(float v){
    int o = __builtin_amdgcn_update_dpp(__float_as_int(v), __float_as_int(v),
                                        CTRL, 0xf, 0xf, false);
    return fmaxf(v, __int_as_float(o));
}
template<int CTRL>
__device__ __forceinline__ float dpp_minf(float v){
    int o = __builtin_amdgcn_update_dpp(__float_as_int(v), __float_as_int(v),
                                        CTRL, 0xf, 0xf, false);
    return fminf(v, __int_as_float(o));
}
__device__ __forceinline__ float wfmax64(float v){
    v = dpp_maxf<0x111>(v);
    v = dpp_maxf<0x112>(v);
    v = dpp_maxf<0x114>(v);
    v = dpp_maxf<0x118>(v);
    v = dpp_maxf<0x142>(v);  // row_bcast:15
    v = dpp_maxf<0x143>(v);  // row_bcast:31
    return __int_as_float(__builtin_amdgcn_readlane(__float_as_int(v), 63));
}
__device__ __forceinline__ float wfmin64(float v){
    v = dpp_minf<0x111>(v);
    v = dpp_minf<0x112>(v);
    v = dpp_minf<0x114>(v);
    v = dpp_minf<0x118>(v);
    v = dpp_minf<0x142>(v);
    v = dpp_minf<0x143>(v);
    return __int_as_float(__builtin_amdgcn_readlane(__float_as_int(v), 63));
}

__device__ __forceinline__ unsigned spread4(unsigned x){
    x = (x | (x<<2)) & 0x33u;
    x = (x | (x<<1)) & 0x55u;
    return x;
}
__device__ __forceinline__ unsigned cell_of(float4 pr){
    unsigned cx = min(15, (int)(pr.x*16.0f));
    unsigned cy = min(15, (int)(pr.y*16.0f));
    return (spread4(cy)<<1) | spread4(cx);
}

// ---- sort stage: partial hist (+init duties) -> scatter (local scan) ----
__global__ __launch_bounds__(1024) void k_hist(const float* __restrict__ priors,
        unsigned* __restrict__ histp, ull* __restrict__ bp, float* __restrict__ accs,
        int* __restrict__ done, unsigned* __restrict__ cursor, int* __restrict__ tcur){
    const int tid = threadIdx.x;
    __shared__ unsigned lh[256];
    if (tid < 256) lh[tid] = 0;
    if (blockIdx.x == 0){          // zero bp (2048 u64)
        bp[tid] = 0ull; bp[tid + 1024] = 0ull;
    } else if (blockIdx.x == 1){   // zero lsum/csum/npos/sS + ticket + cursors
        if (tid < 256) accs[tid] = 0.f;
        if (tid == 256) *done = 0;
        if (tid == 257) *tcur = 0;
        if (tid >= 512 && tid < 768) cursor[tid - 512] = 0u;
    }
    __syncthreads();
    const int p = blockIdx.x*1024 + tid;
    atomicAdd(&lh[cell_of(((const float4*)priors)[p])], 1u);
    __syncthreads();
    if (tid < 256) histp[blockIdx.x*256 + tid] = lh[tid];
}

// scatter with block-local exclusive scan of the 256-bin histogram; intra-cell
// slot via global cursor (nondeterministic order, output order-invariant).
__global__ __launch_bounds__(1024) void k_scatter(const float* __restrict__ priors,
        const unsigned* __restrict__ histp, unsigned* __restrict__ cursor,
        int* __restrict__ ipos, float4* __restrict__ pf4, float2* __restrict__ meta){
    const int tid = threadIdx.x;
    __shared__ unsigned s[256];
    unsigned v = 0;
    if (tid < 256){
        #pragma unroll
        for (int q=0;q<GX;q++) v += histp[q*256 + tid];
        s[tid] = v;
    }
    __syncthreads();
    for (int d=1; d<256; d<<=1){
        unsigned add = (tid < 256 && tid >= d) ? s[tid-d] : 0u;
        __syncthreads();
        if (tid < 256) s[tid] += add;
        __syncthreads();
    }
    if (tid < 256) s[tid] -= v;    // exclusive base
    __syncthreads();
    const int p = blockIdx.x*1024 + tid;
    float4 pr = ((const float4*)priors)[p];
    unsigned c = cell_of(pr);
    unsigned pos = s[c] + atomicAdd(&cursor[c], 1u);
    float hw = pr.z*0.5f, hh = pr.w*0.5f;
    float x0 = pr.x-hw, y0 = pr.y-hh, x1 = pr.x+hw, y1 = pr.y+hh;
    pf4[pos]  = make_float4(x0,y0,x1,y1);
    meta[pos] = make_float2((x1-x0)*(y1-y0), __uint_as_float((unsigned)p));
    ipos[p]   = (int)pos;
}

// ---- fused match + tail: DYNAMIC WORK QUEUE ----
// 2048 blocks x 128 thr (2 independent waves). Task = (b, 128-position
// segment of the sorted priors); 12800 tasks, ~3 per wave -> balanced
// makespan. Wave-private LDS target tile (no block barriers at all).
// Per-task body identical to round-20 (DPP reductions, rational argmax).
__global__ __launch_bounds__(128) void k_main(
        const float4* __restrict__ pf4, const float2* __restrict__ meta,
        const float* __restrict__ loc, const float* __restrict__ conf,
        const float* __restrict__ priors, const float* __restrict__ targets,
        int* __restrict__ tcur,
        ull* __restrict__ bp, float* __restrict__ vals,
        float* __restrict__ lsum_b, float* __restrict__ csum_b, int* __restrict__ npos_b){
    const int tid = threadIdx.x;
    const int lane = tid & 63;
    const int wid = tid >> 6;
    __shared__ float4 s_tb[2][OO];
    __shared__ float  s_ta[2][OO];
    __shared__ int    s_lab[2][OO];
    int curb = -1;

    for (;;){
        int task = 0;
        if (lane == 0) task = atomicAdd(tcur, 1);
        task = __shfl(task, 0);
        if (task >= NTASK) break;
        const int b   = task / 200;
        const int seg = task - b*200;
        const int pos0 = seg*128 + lane;

        if (b != curb){
            if (lane < OO){
                const float* t = targets + ((size_t)b*OO + lane)*5;
                float x0=t[0],y0=t[1],x1=t[2],y1=t[3];
                s_tb[wid][lane] = make_float4(x0,y0,x1,y1);
                s_ta[wid][lane] = (x1-x0)*(y1-y0);
                s_lab[wid][lane]= (int)t[4];
            }
            curb = b;   // wave-private LDS: in-wave waitcnt ordering suffices
        }

        float px0[2],py0[2],px1[2],py1[2],pa[2]; int pg[2];
        #pragma unroll
        for (int j=0;j<2;j++){
            float4 q = pf4[pos0 + j*64];
            float2 mt = meta[pos0 + j*64];
            px0[j]=q.x; py0[j]=q.y; px1[j]=q.z; py1[j]=q.w;
            pa[j]=mt.x; pg[j]=(int)__float_as_uint(mt.y);
        }
        float2 cdv[2];
        #pragma unroll
        for (int j=0;j<2;j++) cdv[j] = ((const float2*)conf)[(size_t)b*PP + pg[j]];

        // exact segment bbox via DPP
        float wx0 = wfmin64(fminf(px0[0],px0[1]));
        float wy0 = wfmin64(fminf(py0[0],py0[1]));
        float wx1 = wfmax64(fmaxf(px1[0],px1[1]));
        float wy1 = wfmax64(fmaxf(py1[0],py1[1]));
        bool ov = false;
        if (lane < OO){
            float4 tb = s_tb[wid][lane];
            ov = (tb.x < wx1) && (tb.z > wx0) && (tb.y < wy1) && (tb.w > wy0);
        }
        ull mm = __ballot(ov);

        float binter[2]={0.f,0.f}, bs[2]={1.f,1.f};
        int bi[2]={0,0};

        while (mm){
            const int t = (int)__builtin_ctzll(mm); mm &= mm-1;
            float4 tb = s_tb[wid][t];
            float ta = s_ta[wid][t];
            float cin=0.f, csn=1.f; unsigned cp=0u;
            #pragma unroll
            for (int j=0;j<2;j++){
                float ltx=fmaxf(tb.x,px0[j]), lty=fmaxf(tb.y,py0[j]);
                float rbx=fminf(tb.z,px1[j]), rby=fminf(tb.w,py1[j]);
                float ww=fmaxf(rbx-ltx,0.f), hh=fmaxf(rby-lty,0.f);
                float inter=ww*hh;
                float s = ta + pa[j];
                bool u1 = inter*bs[j] > binter[j]*s;   // per-prior argmax (exact rational)
                binter[j] = u1?inter:binter[j]; bs[j] = u1?s:bs[j]; bi[j] = u1?t:bi[j];
                bool u2 = inter*csn > cin*s;           // per-truth argmax (lane-local)
                cin = u2?inter:cin; csn = u2?s:csn; cp = u2?(unsigned)pg[j]:cp;
            }
            float iou = cin / (csn - cin);             // reference f32 rounding
            float miou = wfmax64(iou);                 // DPP max, VALU pipe
            if (miou > 0.f && iou == miou){            // usually exactly 1 lane
                ull key = ((ull)__float_as_uint(iou)<<32)
                        | (ull)(0xFFFFFFFFu - cp);     // tie -> smaller global p
                atomicMax(&bp[b*OO + t], key);
            }
        }

        // tail: conf/lse/vals + positive accumulation (forcing in k_selfix)
        float l_ls=0.f, l_cs=0.f; int l_np=0;
        #pragma unroll
        for (int j=0;j<2;j++){
            float biou = binter[j] / (bs[j] - binter[j]);
            int c = (biou < TH) ? 0 : (s_lab[wid][bi[j]] + 1);
            float2 cd = cdv[j];
            float mx = fmaxf(cd.x, cd.y);
            float lse = mx + log1pf(expf(fminf(cd.x,cd.y)-mx));
            float lca = lse - ((c>=1)? cd.y : cd.x);
            bool pos = c>0;
            vals[(size_t)b*PP + pos0 + j*64] = pos ? 0.f : lca;   // coalesced
            if (pos){
                float4 pr = ((const float4*)priors)[pg[j]];
                float4 tb = s_tb[wid][bi[j]];
                float4 ld = ((const float4*)loc)[(size_t)b*PP + pg[j]];
                l_ls += locloss(tb.x,tb.y,tb.z,tb.w, pr, ld);
                l_cs += lca; l_np++;
            }
        }
        #pragma unroll
        for (int d=1; d<64; d<<=1){
            l_ls += __shfl_xor(l_ls,d);
            l_cs += __shfl_xor(l_cs,d);
            l_np += __shfl_xor(l_np,d);
        }
        if (lane==0 && l_np){
            atomicAdd(&lsum_b[b], l_ls);
            atomicAdd(&csum_b[b], l_cs);
            atomicAdd(&npos_b[b], l_np);
        }
    }
}

// Descending-bin scan over h[0..N-1] by one 64-lane wave (C bins/lane).
__device__ __forceinline__ void scan_desc(const unsigned* h, int N, int C,
                                          unsigned kX, unsigned* s_b, unsigned* s_kN,
                                          int lane){
    int base = N - 1 - C*lane;
    unsigned csum = 0;
    for (int q=0;q<C;q++) csum += h[base-q];
    unsigned inc = csum;
    #pragma unroll
    for (int d=1; d<64; d<<=1){
        unsigned o = __shfl_up(inc, d);
        if (lane >= d) inc += o;
    }
    unsigned excl = inc - csum;
    if (excl < kX && kX <= inc){
        unsigned cum = excl;
        for (int q=0;q<C;q++){
            unsigned hv = h[base-q];
            cum += hv;
            if (cum >= kX){ *s_b = (unsigned)(base-q); *s_kN = kX - (cum - hv); break; }
        }
    }
}

// Phase A: forcing fixup. Phase B: exact sum-of-top-k (3-pass radix).
// Last block (device ticket) performs the final cross-batch reduction.
__global__ __launch_bounds__(1024) void k_selfix(
        const float* __restrict__ loc, const float* __restrict__ conf,
        const float* __restrict__ priors, const float* __restrict__ targets,
        const ull* __restrict__ bp, const int* __restrict__ ipos,
        float* __restrict__ vals,
        float* __restrict__ lsum_b, float* __restrict__ csum_b, int* __restrict__ npos_b,
        float* __restrict__ sS, int* __restrict__ done, float* __restrict__ out){
    const int b = blockIdx.x;
    const int tid = threadIdx.x;
    __shared__ float4 s_tb[OO];
    __shared__ float  s_ta[OO];
    __shared__ int    s_lab[OO];
    __shared__ unsigned s_p[OO];
    __shared__ unsigned h[2048];
    __shared__ unsigned s_bd[3];
    __shared__ unsigned s_kx[3];
    __shared__ float s_sumf, s_S;
    __shared__ unsigned s_cntg;
    __shared__ int s_kint, s_last;
    if (tid < OO){
        const float* tt = targets + ((size_t)b*OO + tid)*5;
        s_tb[tid] = make_float4(tt[0],tt[1],tt[2],tt[3]);
        s_ta[tid] = (tt[2]-tt[0])*(tt[3]-tt[1]);
        s_lab[tid]= (int)tt[4];
        ull bk = bp[b*OO + tid];
        s_p[tid]  = (bk == 0) ? 0u : (0xFFFFFFFFu - (unsigned)(bk & 0xFFFFFFFFull));
    }
    h[tid] = 0; h[tid+1024] = 0;
    if (tid == 0){ s_sumf = 0.f; s_cntg = 0; s_S = 0.f; }
    __syncthreads();
    if (tid < OO){
        unsigned p = s_p[tid];
        bool last = true;
        for (int t2=tid+1; t2<OO; t2++) if (s_p[t2]==p) last = false;
        if (last){
            // recompute unforced state for prior p — identical semantics to k_main
            float4 pr = ((const float4*)priors)[p];
            float hw=pr.z*0.5f, hh=pr.w*0.5f;
            float qx0=pr.x-hw, qy0=pr.y-hh, qx1=pr.x+hw, qy1=pr.y+hh;
            float qa=(qx1-qx0)*(qy1-qy0);
            float binter=0.f, bss=1.f; int bi=0;
            for (int k2=0;k2<OO;k2++){
                float4 tb = s_tb[k2];
                float ltx=fmaxf(tb.x,qx0), lty=fmaxf(tb.y,qy0);
                float rbx=fminf(tb.z,qx1), rby=fminf(tb.w,qy1);
                float w=fmaxf(rbx-ltx,0.f), h2=fmaxf(rby-lty,0.f);
                float inter=w*h2; float s=s_ta[k2]+qa;
                if (inter*bss > binter*s){ binter=inter; bss=s; bi=k2; }
            }
            float biou = binter/(bss-binter);
            int  c0   = (biou < TH) ? 0 : (s_lab[bi] + 1);
            bool pos0 = c0 > 0;
            float2 cd = ((const float2*)conf)[(size_t)b*PP + p];
            float mx  = fmaxf(cd.x, cd.y);
            float lse = mx + log1pf(expf(fminf(cd.x,cd.y)-mx));
            float lca0 = lse - ((c0 >= 1) ? cd.y : cd.x);
            int   cn   = s_lab[tid] + 1;
            float lcan = lse - ((cn >= 1) ? cd.y : cd.x);
            float4 ld  = ((const float4*)loc)[(size_t)b*PP + p];
            float4 tbn = s_tb[tid];
            float lln = locloss(tbn.x,tbn.y,tbn.z,tbn.w, pr, ld);
            float ll0 = 0.f;
            if (pos0){
                float4 tb0 = s_tb[bi];
                ll0 = locloss(tb0.x,tb0.y,tb0.z,tb0.w, pr, ld);
            }
            atomicAdd(&lsum_b[b], lln - ll0);
            atomicAdd(&csum_b[b], lcan - (pos0 ? lca0 : 0.f));
            if (!pos0) atomicAdd(&npos_b[b], 1);
            vals[(size_t)b*PP + ipos[p]] = 0.f;     // vals is in sorted order
        }
    }
    __syncthreads();
    if (tid == 0){
        int np = atomicAdd(&npos_b[b], 0);
        int kk = 3*np; if (kk > PP-1) kk = PP-1;
        s_kint = kk;
    }
    __syncthreads();
    const int k = s_kint;
    const unsigned* g = (const unsigned*)(vals + (size_t)b*PP);
    unsigned uv[25];
    #pragma unroll
    for (int i2=0;i2<25;i2++) uv[i2] = g[tid + (i2<<10)];

    if (k > 0){
        #pragma unroll
        for (int i2=0;i2<25;i2++) atomicAdd(&h[uv[i2]>>20], 1u);
        __syncthreads();
        if (tid < 64) scan_desc(h, 2048, 32, (unsigned)k, &s_bd[0], &s_kx[0], tid);
        __syncthreads();
        const unsigned bA = s_bd[0];
        const unsigned kB = s_kx[0];
        h[tid] = 0;
        __syncthreads();
        #pragma unroll
        for (int i2=0;i2<25;i2++)
            if ((uv[i2]>>20) == bA) atomicAdd(&h[(uv[i2]>>10)&1023], 1u);
        __syncthreads();
        if (tid < 64) scan_desc(h, 1024, 16, kB, &s_bd[1], &s_kx[1], tid);
        __syncthreads();
        const unsigned pref21 = (bA<<10) | s_bd[1];
        const unsigned kC = s_kx[1];
        h[tid] = 0;
        __syncthreads();
        #pragma unroll
        for (int i2=0;i2<25;i2++)
            if ((uv[i2]>>10) == pref21) atomicAdd(&h[uv[i2]&1023], 1u);
        __syncthreads();
        if (tid < 64) scan_desc(h, 1024, 16, kC, &s_bd[2], &s_kx[2], tid);
        __syncthreads();
        const unsigned T = (pref21<<10) | s_bd[2];
        unsigned cg = 0; float sg = 0.f;
        #pragma unroll
        for (int i2=0;i2<25;i2++){
            unsigned u = uv[i2];
            if (u > T){ cg++; sg += __uint_as_float(u); }
        }
        #pragma unroll
        for (int d=32; d; d>>=1){ cg += __shfl_down(cg,d); sg += __shfl_down(sg,d); }
        if ((tid & 63)==0){ if (cg) atomicAdd(&s_cntg, cg); atomicAdd(&s_sumf, sg); }
        __syncthreads();
        if (tid == 0)
            s_S = s_sumf + (float)(k - (int)s_cntg) * __uint_as_float(T);
        __syncthreads();
    }
    if (tid == 0){
        atomicExch(&sS[b], s_S);
        __threadfence();
        int old = atomicAdd(done, 1);
        s_last = (old == BB-1) ? 1 : 0;
    }
    __syncthreads();
    if (s_last && tid < 64){
        float ls = atomicAdd(&lsum_b[tid], 0.f);
        float cs = atomicAdd(&csum_b[tid], 0.f) + atomicAdd(&sS[tid], 0.f);
        int   np = atomicAdd(&npos_b[tid], 0);
        #pragma unroll
        for (int d=32; d; d>>=1){
            ls += __shfl_down(ls,d);
            cs += __shfl_down(cs,d);
            np += __shfl_down(np,d);
        }
        if (tid == 0){
            float N = fmaxf((float)np, 1.f);
            out[0] = ls / N;
            out[1] = cs / N;
        }
    }
}

extern "C" void kernel_launch(void* const* d_in, const int* in_sizes, int n_in,
                              void* d_out, int out_size, void* d_ws, size_t ws_size,
                              hipStream_t stream){
    const float* loc     = (const float*)d_in[0];
    const float* conf    = (const float*)d_in[1];
    const float* priors  = (const float*)d_in[2];
    const float* targets = (const float*)d_in[3];
    float* out = (float*)d_out;
    char* ws = (char*)d_ws;

    ull*      bp     = (ull*)(ws + WS_BP);
    float*    lsum_b = (float*)(ws + WS_LSUM);
    float*    csum_b = (float*)(ws + WS_CSUM);
    int*      npos_b = (int*)(ws + WS_NPOS);
    float*    sS     = (float*)(ws + WS_SS);
    int*      done   = (int*)(ws + WS_DONE);
    int*      tcur   = (int*)(ws + WS_DONE + 4);
    unsigned* histp  = (unsigned*)(ws + WS_HISTP);
    unsigned* cursor = (unsigned*)(ws + WS_CURS);
    int*      ipos   = (int*)(ws + WS_IPOS);
    float4*   pf4    = (float4*)(ws + WS_PF4);
    float2*   meta   = (float2*)(ws + WS_META);
    float*    vals   = (float*)(ws + WS_VALS);

    k_hist<<<GX, 1024, 0, stream>>>(priors, histp, bp, lsum_b, done, cursor, tcur);
    k_scatter<<<GX, 1024, 0, stream>>>(priors, histp, cursor, ipos, pf4, meta);
    k_main<<<2048, 128, 0, stream>>>(pf4, meta, loc, conf, priors, targets, tcur,
                                     bp, vals, lsum_b, csum_b, npos_b);
    k_selfix<<<BB, 1024, 0, stream>>>(loc, conf, priors, targets, bp, ipos, vals,
                                      lsum_b, csum_b, npos_b, sS, done, out);
}

// Round 22
// 90.151 us; speedup vs baseline: 2.7467x; 2.7467x over previous
//
#include <hip/hip_runtime.h>

typedef unsigned long long ull;

#define BB 64
#define PP 25600
#define OO 32
#define TH 0.35f
#define GX 25

// ws layout
#define WS_BP     0           // 16384 B (zeroed by k_hist block 0; bp==0 <=> all-zero row -> p=0)
#define WS_LSUM   16384       // 256 B (zeroed by k_hist block 1)
#define WS_CSUM   16640
#define WS_NPOS   16896
#define WS_SS     17152
#define WS_DONE   17408       // ticket
#define WS_HISTP  17664       // 25600 B
#define WS_CURS   43264       // 1024 B (per-cell cursors, zeroed by k_hist block 1)
#define WS_IPOS   44288       // 102400 B
#define WS_PF4    146688      // 409600 B
#define WS_META   556288      // 204800 B
#define WS_VALS   761088      // 6553600 B

__device__ __forceinline__ float sl1f(float d){
    float ad = fabsf(d);
    return ad < 1.f ? 0.5f*ad*ad : ad - 0.5f;
}

__device__ __forceinline__ float locloss(float x0,float y0,float x1,float y1,
                                         float4 pr, float4 ld){
    float gx = ((x0+x1)*0.5f - pr.x) / (0.1f*pr.z);
    float gy = ((y0+y1)*0.5f - pr.y) / (0.1f*pr.w);
    float gw = logf((x1-x0)/pr.z) / 0.2f;
    float gh = logf((y1-y0)/pr.w) / 0.2f;
    return sl1f(ld.x-gx)+sl1f(ld.y-gy)+sl1f(ld.z-gw)+sl1f(ld.w-gh);
}

// DPP cross-lane max/min (old=v, bound_ctrl=false -> invalid lanes identity).
template<int CTRL>
__device__ __forceinline__ float dpp_maxf(float v){
    int o = __builtin_amdgcn_update_dpp(__float_as_int(v), __float_as_int(v),
                                        CTRL, 0xf, 0xf, false);
    return fmaxf(v, __int_as_float(o));
}
template<int CTRL>
__device__ __forceinline__ float dpp_minf(float v){
    int o = __builtin_amdgcn_update_dpp(__float_as_int(v), __float_as_int(v),
                                        CTRL, 0xf, 0xf, false);
    return fminf(v, __int_as_float(o));
}
__device__ __forceinline__ float wfmax64(float v){
    v = dpp_maxf<0x111>(v);
    v = dpp_maxf<0x112>(v);
    v = dpp_maxf<0x114>(v);
    v = dpp_maxf<0x118>(v);
    v = dpp_maxf<0x142>(v);  // row_bcast:15
    v = dpp_maxf<0x143>(v);  // row_bcast:31
    return __int_as_float(__builtin_amdgcn_readlane(__float_as_int(v), 63));
}
__device__ __forceinline__ float wfmin64(float v){
    v = dpp_minf<0x111>(v);
    v = dpp_minf<0x112>(v);
    v = dpp_minf<0x114>(v);
    v = dpp_minf<0x118>(v);
    v = dpp_minf<0x142>(v);
    v = dpp_minf<0x143>(v);
    return __int_as_float(__builtin_amdgcn_readlane(__float_as_int(v), 63));
}

__device__ __forceinline__ unsigned spread4(unsigned x){
    x = (x | (x<<2)) & 0x33u;
    x = (x | (x<<1)) & 0x55u;
    return x;
}
__device__ __forceinline__ unsigned cell_of(float4 pr){
    unsigned cx = min(15, (int)(pr.x*16.0f));
    unsigned cy = min(15, (int)(pr.y*16.0f));
    return (spread4(cy)<<1) | spread4(cx);
}

// ---- sort stage: partial hist (+init duties) -> scatter (local scan) ----
__global__ __launch_bounds__(1024) void k_hist(const float* __restrict__ priors,
        unsigned* __restrict__ histp, ull* __restrict__ bp, float* __restrict__ accs,
        int* __restrict__ done, unsigned* __restrict__ cursor){
    const int tid = threadIdx.x;
    __shared__ unsigned lh[256];
    if (tid < 256) lh[tid] = 0;
    if (blockIdx.x == 0){          // zero bp (2048 u64)
        bp[tid] = 0ull; bp[tid + 1024] = 0ull;
    } else if (blockIdx.x == 1){   // zero lsum/csum/npos/sS + ticket + cursors
        if (tid < 256) accs[tid] = 0.f;
        if (tid == 256) *done = 0;
        if (tid >= 512 && tid < 768) cursor[tid - 512] = 0u;
    }
    __syncthreads();
    const int p = blockIdx.x*1024 + tid;
    atomicAdd(&lh[cell_of(((const float4*)priors)[p])], 1u);
    __syncthreads();
    if (tid < 256) histp[blockIdx.x*256 + tid] = lh[tid];
}

// scatter with block-local exclusive scan of the 256-bin histogram; intra-cell
// slot via global cursor (nondeterministic order, output order-invariant).
__global__ __launch_bounds__(1024) void k_scatter(const float* __restrict__ priors,
        const unsigned* __restrict__ histp, unsigned* __restrict__ cursor,
        int* __restrict__ ipos, float4* __restrict__ pf4, float2* __restrict__ meta){
    const int tid = threadIdx.x;
    __shared__ unsigned s[256];
    unsigned v = 0;
    if (tid < 256){
        #pragma unroll
        for (int q=0;q<GX;q++) v += histp[q*256 + tid];
        s[tid] = v;
    }
    __syncthreads();
    for (int d=1; d<256; d<<=1){
        unsigned add = (tid < 256 && tid >= d) ? s[tid-d] : 0u;
        __syncthreads();
        if (tid < 256) s[tid] += add;
        __syncthreads();
    }
    if (tid < 256) s[tid] -= v;    // exclusive base
    __syncthreads();
    const int p = blockIdx.x*1024 + tid;
    float4 pr = ((const float4*)priors)[p];
    unsigned c = cell_of(pr);
    unsigned pos = s[c] + atomicAdd(&cursor[c], 1u);
    float hw = pr.z*0.5f, hh = pr.w*0.5f;
    float x0 = pr.x-hw, y0 = pr.y-hh, x1 = pr.x+hw, y1 = pr.y+hh;
    pf4[pos]  = make_float4(x0,y0,x1,y1);
    meta[pos] = make_float2((x1-x0)*(y1-y0), __uint_as_float((unsigned)p));
    ipos[p]   = (int)pos;
}

// ---- fused match + tail (3200 x 128 thr, 2 indep waves, 256 pos/wave,
// DPP reductions, XCD-grouped) ----
__global__ __launch_bounds__(128) void k_main(
        const float4* __restrict__ pf4, const float2* __restrict__ meta,
        const float* __restrict__ loc, const float* __restrict__ conf,
        const float* __restrict__ priors, const float* __restrict__ targets,
        ull* __restrict__ bp, float* __restrict__ vals,
        float* __restrict__ lsum_b, float* __restrict__ csum_b, int* __restrict__ npos_b){
    const int bid = blockIdx.x;
    const int xcd = bid & 7;
    const int i   = bid >> 3;       // 0..399
    const int g   = i / 50;         // 0..7
    const int w   = i - g*50;       // 0..49
    const int b   = (g<<3) | xcd;
    const int tid = threadIdx.x;
    const int lane = tid & 63;
    const int wid = tid >> 6;
    const int pos0 = w*512 + wid*256 + lane;

    __shared__ float4 s_tb[OO];
    __shared__ float  s_ta[OO];
    __shared__ int    s_lab[OO];
    if (tid < OO){
        const float* t = targets + ((size_t)b*OO + tid)*5;
        float x0=t[0],y0=t[1],x1=t[2],y1=t[3];
        s_tb[tid] = make_float4(x0,y0,x1,y1);
        s_ta[tid] = (x1-x0)*(y1-y0);
        s_lab[tid]= (int)t[4];
    }
    __syncthreads();                 // only barrier; waves independent after

    float px0[4],py0[4],px1[4],py1[4],pa[4]; int pg[4];
    #pragma unroll
    for (int j=0;j<4;j++){
        float4 q = pf4[pos0 + j*64];
        float2 mt = meta[pos0 + j*64];
        px0[j]=q.x; py0[j]=q.y; px1[j]=q.z; py1[j]=q.w;
        pa[j]=mt.x; pg[j]=(int)__float_as_uint(mt.y);
    }
    // preload conf gathers; consumed in tail (latency hidden by match loop)
    float2 cdv[4];
    #pragma unroll
    for (int j=0;j<4;j++) cdv[j] = ((const float2*)conf)[(size_t)b*PP + pg[j]];

    // exact wave bbox via DPP (VALU pipe, once per wave)
    float wx0 = wfmin64(fminf(fminf(px0[0],px0[1]),fminf(px0[2],px0[3])));
    float wy0 = wfmin64(fminf(fminf(py0[0],py0[1]),fminf(py0[2],py0[3])));
    float wx1 = wfmax64(fmaxf(fmaxf(px1[0],px1[1]),fmaxf(px1[2],px1[3])));
    float wy1 = wfmax64(fmaxf(fmaxf(py1[0],py1[1]),fmaxf(py1[2],py1[3])));
    bool ov = false;
    if (lane < OO){
        float4 tb = s_tb[lane];
        ov = (tb.x < wx1) && (tb.z > wx0) && (tb.y < wy1) && (tb.w > wy0);
    }
    ull mm = __ballot(ov);

    float binter[4]={0.f,0.f,0.f,0.f}, bs[4]={1.f,1.f,1.f,1.f};
    int bi[4]={0,0,0,0};

    while (mm){
        const int t = (int)__builtin_ctzll(mm); mm &= mm-1;
        float4 tb = s_tb[t];
        float ta = s_ta[t];
        float cin=0.f, csn=1.f; unsigned cp=0u;
        #pragma unroll
        for (int j=0;j<4;j++){
            float ltx=fmaxf(tb.x,px0[j]), lty=fmaxf(tb.y,py0[j]);
            float rbx=fminf(tb.z,px1[j]), rby=fminf(tb.w,py1[j]);
            float ww=fmaxf(rbx-ltx,0.f), hh=fmaxf(rby-lty,0.f);
            float inter=ww*hh;
            float s = ta + pa[j];
            bool u1 = inter*bs[j] > binter[j]*s;   // per-prior argmax (exact rational)
            binter[j] = u1?inter:binter[j]; bs[j] = u1?s:bs[j]; bi[j] = u1?t:bi[j];
            bool u2 = inter*csn > cin*s;           // per-truth argmax (lane-local)
            cin = u2?inter:cin; csn = u2?s:csn; cp = u2?(unsigned)pg[j]:cp;
        }
        float iou = cin / (csn - cin);             // reference f32 rounding
        float miou = wfmax64(iou);                 // DPP max, VALU pipe
        if (miou > 0.f && iou == miou){            // usually exactly 1 lane
            ull key = ((ull)__float_as_uint(iou)<<32)
                    | (ull)(0xFFFFFFFFu - cp);     // tie -> smaller global p
            atomicMax(&bp[b*OO + t], key);
        }
    }

    // tail: conf/lse/vals + positive accumulation (forcing fixed in k_selfix)
    float l_ls=0.f, l_cs=0.f; int l_np=0;
    #pragma unroll
    for (int j=0;j<4;j++){
        float biou = binter[j] / (bs[j] - binter[j]);
        int c = (biou < TH) ? 0 : (s_lab[bi[j]] + 1);
        float2 cd = cdv[j];
        float mx = fmaxf(cd.x, cd.y);
        float lse = mx + log1pf(expf(fminf(cd.x,cd.y)-mx));
        float lca = lse - ((c>=1)? cd.y : cd.x);
        bool pos = c>0;
        vals[(size_t)b*PP + pos0 + j*64] = pos ? 0.f : lca;   // sorted order, coalesced
        if (pos){
            float4 pr = ((const float4*)priors)[pg[j]];
            float4 tb = s_tb[bi[j]];
            float4 ld = ((const float4*)loc)[(size_t)b*PP + pg[j]];
            l_ls += locloss(tb.x,tb.y,tb.z,tb.w, pr, ld);
            l_cs += lca; l_np++;
        }
    }
    #pragma unroll
    for (int d=1; d<64; d<<=1){
        l_ls += __shfl_xor(l_ls,d);
        l_cs += __shfl_xor(l_cs,d);
        l_np += __shfl_xor(l_np,d);
    }
    if (lane==0 && l_np){
        atomicAdd(&lsum_b[b], l_ls);
        atomicAdd(&csum_b[b], l_cs);
        atomicAdd(&npos_b[b], l_np);
    }
}

// Descending-bin scan over h[0..N-1] by one 64-lane wave (C bins/lane).
__device__ __forceinline__ void scan_desc(const unsigned* h, int N, int C,
                                          unsigned kX, unsigned* s_b, unsigned* s_kN,
                                          int lane){
    int base = N - 1 - C*lane;
    unsigned csum = 0;
    for (int q=0;q<C;q++) csum += h[base-q];
    unsigned inc = csum;
    #pragma unroll
    for (int d=1; d<64; d<<=1){
        unsigned o = __shfl_up(inc, d);
        if (lane >= d) inc += o;
    }
    unsigned excl = inc - csum;
    if (excl < kX && kX <= inc){
        unsigned cum = excl;
        for (int q=0;q<C;q++){
            unsigned hv = h[base-q];
            cum += hv;
            if (cum >= kX){ *s_b = (unsigned)(base-q); *s_kN = kX - (cum - hv); break; }
        }
    }
}

// Phase A: forcing fixup. Phase B: exact sum-of-top-k (3-pass radix).
// Last block (device ticket) performs the final cross-batch reduction.
__global__ __launch_bounds__(1024) void k_selfix(
        const float* __restrict__ loc, const float* __restrict__ conf,
        const float* __restrict__ priors, const float* __restrict__ targets,
        const ull* __restrict__ bp, const int* __restrict__ ipos,
        float* __restrict__ vals,
        float* __restrict__ lsum_b, float* __restrict__ csum_b, int* __restrict__ npos_b,
        float* __restrict__ sS, int* __restrict__ done, float* __restrict__ out){
    const int b = blockIdx.x;
    const int tid = threadIdx.x;
    __shared__ float4 s_tb[OO];
    __shared__ float  s_ta[OO];
    __shared__ int    s_lab[OO];
    __shared__ unsigned s_p[OO];
    __shared__ unsigned h[2048];
    __shared__ unsigned s_bd[3];
    __shared__ unsigned s_kx[3];
    __shared__ float s_sumf, s_S;
    __shared__ unsigned s_cntg;
    __shared__ int s_kint, s_last;
    if (tid < OO){
        const float* tt = targets + ((size_t)b*OO + tid)*5;
        s_tb[tid] = make_float4(tt[0],tt[1],tt[2],tt[3]);
        s_ta[tid] = (tt[2]-tt[0])*(tt[3]-tt[1]);
        s_lab[tid]= (int)tt[4];
        ull bk = bp[b*OO + tid];
        s_p[tid]  = (bk == 0) ? 0u : (0xFFFFFFFFu - (unsigned)(bk & 0xFFFFFFFFull));
    }
    h[tid] = 0; h[tid+1024] = 0;
    if (tid == 0){ s_sumf = 0.f; s_cntg = 0; s_S = 0.f; }
    __syncthreads();
    if (tid < OO){
        unsigned p = s_p[tid];
        bool last = true;
        for (int t2=tid+1; t2<OO; t2++) if (s_p[t2]==p) last = false;
        if (last){
            // recompute unforced state for prior p — identical semantics to k_main
            float4 pr = ((const float4*)priors)[p];
            float hw=pr.z*0.5f, hh=pr.w*0.5f;
            float qx0=pr.x-hw, qy0=pr.y-hh, qx1=pr.x+hw, qy1=pr.y+hh;
            float qa=(qx1-qx0)*(qy1-qy0);
            float binter=0.f, bss=1.f; int bi=0;
            for (int k2=0;k2<OO;k2++){
                float4 tb = s_tb[k2];
                float ltx=fmaxf(tb.x,qx0), lty=fmaxf(tb.y,qy0);
                float rbx=fminf(tb.z,qx1), rby=fminf(tb.w,qy1);
                float w=fmaxf(rbx-ltx,0.f), h2=fmaxf(rby-lty,0.f);
                float inter=w*h2; float s=s_ta[k2]+qa;
                if (inter*bss > binter*s){ binter=inter; bss=s; bi=k2; }
            }
            float biou = binter/(bss-binter);
            int  c0   = (biou < TH) ? 0 : (s_lab[bi] + 1);
            bool pos0 = c0 > 0;
            float2 cd = ((const float2*)conf)[(size_t)b*PP + p];
            float mx  = fmaxf(cd.x, cd.y);
            float lse = mx + log1pf(expf(fminf(cd.x,cd.y)-mx));
            float lca0 = lse - ((c0 >= 1) ? cd.y : cd.x);
            int   cn   = s_lab[tid] + 1;
            float lcan = lse - ((cn >= 1) ? cd.y : cd.x);
            float4 ld  = ((const float4*)loc)[(size_t)b*PP + p];
            float4 tbn = s_tb[tid];
            float lln = locloss(tbn.x,tbn.y,tbn.z,tbn.w, pr, ld);
            float ll0 = 0.f;
            if (pos0){
                float4 tb0 = s_tb[bi];
                ll0 = locloss(tb0.x,tb0.y,tb0.z,tb0.w, pr, ld);
            }
            atomicAdd(&lsum_b[b], lln - ll0);
            atomicAdd(&csum_b[b], lcan - (pos0 ? lca0 : 0.f));
            if (!pos0) atomicAdd(&npos_b[b], 1);
            vals[(size_t)b*PP + ipos[p]] = 0.f;     // vals is in sorted order
        }
    }
    __syncthreads();
    if (tid == 0){
        int np = atomicAdd(&npos_b[b], 0);
        int kk = 3*np; if (kk > PP-1) kk = PP-1;
        s_kint = kk;
    }
    __syncthreads();
    const int k = s_kint;
    const unsigned* g = (const unsigned*)(vals + (size_t)b*PP);
    unsigned uv[25];
    #pragma unroll
    for (int i2=0;i2<25;i2++) uv[i2] = g[tid + (i2<<10)];

    if (k > 0){
        #pragma unroll
        for (int i2=0;i2<25;i2++) atomicAdd(&h[uv[i2]>>20], 1u);
        __syncthreads();
        if (tid < 64) scan_desc(h, 2048, 32, (unsigned)k, &s_bd[0], &s_kx[0], tid);
        __syncthreads();
        const unsigned bA = s_bd[0];
        const unsigned kB = s_kx[0];
        h[tid] = 0;
        __syncthreads();
        #pragma unroll
        for (int i2=0;i2<25;i2++)
            if ((uv[i2]>>20) == bA) atomicAdd(&h[(uv[i2]>>10)&1023], 1u);
        __syncthreads();
        if (tid < 64) scan_desc(h, 1024, 16, kB, &s_bd[1], &s_kx[1], tid);
        __syncthreads();
        const unsigned pref21 = (bA<<10) | s_bd[1];
        const unsigned kC = s_kx[1];
        h[tid] = 0;
        __syncthreads();
        #pragma unroll
        for (int i2=0;i2<25;i2++)
            if ((uv[i2]>>10) == pref21) atomicAdd(&h[uv[i2]&1023], 1u);
        __syncthreads();
        if (tid < 64) scan_desc(h, 1024, 16, kC, &s_bd[2], &s_kx[2], tid);
        __syncthreads();
        const unsigned T = (pref21<<10) | s_bd[2];
        unsigned cg = 0; float sg = 0.f;
        #pragma unroll
        for (int i2=0;i2<25;i2++){
            unsigned u = uv[i2];
            if (u > T){ cg++; sg += __uint_as_float(u); }
        }
        #pragma unroll
        for (int d=32; d; d>>=1){ cg += __shfl_down(cg,d); sg += __shfl_down(sg,d); }
        if ((tid & 63)==0){ if (cg) atomicAdd(&s_cntg, cg); atomicAdd(&s_sumf, sg); }
        __syncthreads();
        if (tid == 0)
            s_S = s_sumf + (float)(k - (int)s_cntg) * __uint_as_float(T);
        __syncthreads();
    }
    if (tid == 0){
        atomicExch(&sS[b], s_S);
        __threadfence();
        int old = atomicAdd(done, 1);
        s_last = (old == BB-1) ? 1 : 0;
    }
    __syncthreads();
    if (s_last && tid < 64){
        float ls = atomicAdd(&lsum_b[tid], 0.f);
        float cs = atomicAdd(&csum_b[tid], 0.f) + atomicAdd(&sS[tid], 0.f);
        int   np = atomicAdd(&npos_b[tid], 0);
        #pragma unroll
        for (int d=32; d; d>>=1){
            ls += __shfl_down(ls,d);
            cs += __shfl_down(cs,d);
            np += __shfl_down(np,d);
        }
        if (tid == 0){
            float N = fmaxf((float)np, 1.f);
            out[0] = ls / N;
            out[1] = cs / N;
        }
    }
}

extern "C" void kernel_launch(void* const* d_in, const int* in_sizes, int n_in,
                              void* d_out, int out_size, void* d_ws, size_t ws_size,
                              hipStream_t stream){
    const float* loc     = (const float*)d_in[0];
    const float* conf    = (const float*)d_in[1];
    const float* priors  = (const float*)d_in[2];
    const float* targets = (const float*)d_in[3];
    float* out = (float*)d_out;
    char* ws = (char*)d_ws;

    ull*      bp     = (ull*)(ws + WS_BP);
    float*    lsum_b = (float*)(ws + WS_LSUM);
    float*    csum_b = (float*)(ws + WS_CSUM);
    int*      npos_b = (int*)(ws + WS_NPOS);
    float*    sS     = (float*)(ws + WS_SS);
    int*      done   = (int*)(ws + WS_DONE);
    unsigned* histp  = (unsigned*)(ws + WS_HISTP);
    unsigned* cursor = (unsigned*)(ws + WS_CURS);
    int*      ipos   = (int*)(ws + WS_IPOS);
    float4*   pf4    = (float4*)(ws + WS_PF4);
    float2*   meta   = (float2*)(ws + WS_META);
    float*    vals   = (float*)(ws + WS_VALS);

    k_hist<<<GX, 1024, 0, stream>>>(priors, histp, bp, lsum_b, done, cursor);
    k_scatter<<<GX, 1024, 0, stream>>>(priors, histp, cursor, ipos, pf4, meta);
    k_main<<<GX*BB*2, 128, 0, stream>>>(pf4, meta, loc, conf, priors, targets,
                                        bp, vals, lsum_b, csum_b, npos_b);
    k_selfix<<<BB, 1024, 0, stream>>>(loc, conf, priors, targets, bp, ipos, vals,
                                      lsum_b, csum_b, npos_b, sS, done, out);
}